// Round 7
// baseline (146.211 us; speedup 1.0000x reference)
//
#include <hip/hip_runtime.h>
#include <math.h>

// Problem constants (from reference): B=32, Q=4096, G=32, C=128
#define NB   32
#define BQ   4096
#define GMAX 32
#define NC   128
#define BS   512            // solver threads per block
#define CPT  (BQ / BS)      // 8 contiguous columns per thread: j = tid*8 + k
#define NWAVE (BS / 64)     // 8 waves

#define TQ    32            // q-tile
#define BBS   256           // build block size
#define TPB   8             // q-tiles per build block (pipelined)
#define NTILE (BQ / TQ)     // 128 tiles per (b, row)

// ---------------- Kernel 1: pipelined cost build + row-min partials --------
// cost[b][i][q] = -sem[b,q,lab_i] - 0.5*obj[b,q] + cent[b,q,i] - 2*giou[b,q,i]
// exact f32 per-op rounding in reference order. Also emits per-(i, 32q-tile)
// (min, first-argmin) partials for the solver's warm start.
__launch_bounds__(BBS)
__global__ void build_cost_kernel(const float* __restrict__ sem,
                                  const float* __restrict__ objp,
                                  const float* __restrict__ cent,
                                  const float* __restrict__ giou,
                                  const int*   __restrict__ labels,
                                  const int*   __restrict__ nact,
                                  float* __restrict__ cost,      // [B][G][Q]
                                  float2* __restrict__ rowpart)  // [B][G][NTILE]
{
    const int b   = blockIdx.y;
    const int tg  = blockIdx.x;         // 0..15 (group of TPB tiles)
    const int tid = threadIdx.x;

    __shared__ float sem_sh [2][TQ][NC + 1];     // 2 x 16.5 KB
    __shared__ float cent_sh[2][TQ][GMAX + 1];   // 2 x 4.2 KB
    __shared__ float giou_sh[2][TQ][GMAX + 1];   // 2 x 4.2 KB
    __shared__ int lab_sh[GMAX];

    if (tid < GMAX) lab_sh[tid] = labels[b * GMAX + tid];
    const int ng = nact[b];

    const int qi = tid & (TQ - 1);      // 0..31
    const int ig = tid >> 5;            // 0..7

    const size_t semoff = (size_t)b * BQ * NC;
    const size_t cgoff  = (size_t)b * BQ * GMAX;
    const int q0 = tg * (TPB * TQ);

    // prefetch tile 0 into registers
    float4 sr[4], cr, gr;
    {
        const float4* s4 = (const float4*)(sem + semoff + (size_t)q0 * NC);
#pragma unroll
        for (int x = 0; x < 4; x++) sr[x] = s4[x * BBS + tid];
        const float4* c4 = (const float4*)(cent + cgoff + (size_t)q0 * GMAX);
        const float4* g4 = (const float4*)(giou + cgoff + (size_t)q0 * GMAX);
        cr = c4[tid];
        gr = g4[tid];
    }
    float ho[TPB];
#pragma unroll
    for (int tt = 0; tt < TPB; tt++)
        ho[tt] = __fmul_rn(0.5f, objp[b * BQ + q0 + tt * TQ + qi]);

#pragma unroll
    for (int tt = 0; tt < TPB; tt++) {
        const int buf = tt & 1;
        const int qt  = q0 + tt * TQ;

        // stage registers -> LDS[buf]
#pragma unroll
        for (int x = 0; x < 4; x++) {
            int e  = (x * BBS + tid) * 4;
            int qq = e >> 7, cc = e & (NC - 1);
            sem_sh[buf][qq][cc]     = sr[x].x;
            sem_sh[buf][qq][cc + 1] = sr[x].y;
            sem_sh[buf][qq][cc + 2] = sr[x].z;
            sem_sh[buf][qq][cc + 3] = sr[x].w;
        }
        {
            int e = tid * 4, qq = e >> 5, ii = e & (GMAX - 1);
            cent_sh[buf][qq][ii]     = cr.x;
            cent_sh[buf][qq][ii + 1] = cr.y;
            cent_sh[buf][qq][ii + 2] = cr.z;
            cent_sh[buf][qq][ii + 3] = cr.w;
            giou_sh[buf][qq][ii]     = gr.x;
            giou_sh[buf][qq][ii + 1] = gr.y;
            giou_sh[buf][qq][ii + 2] = gr.z;
            giou_sh[buf][qq][ii + 3] = gr.w;
        }
        __syncthreads();   // one barrier per tile (double-buffer makes it safe)

        // issue next tile's global loads: in flight during this tile's compute
        if (tt + 1 < TPB) {
            const int qn = q0 + (tt + 1) * TQ;
            const float4* s4 = (const float4*)(sem + semoff + (size_t)qn * NC);
#pragma unroll
            for (int x = 0; x < 4; x++) sr[x] = s4[x * BBS + tid];
            const float4* c4 = (const float4*)(cent + cgoff + (size_t)qn * GMAX);
            const float4* g4 = (const float4*)(giou + cgoff + (size_t)qn * GMAX);
            cr = c4[tid];
            gr = g4[tid];
        }

        // compute tile tt: thread = (qi, ig), rows i = ig, ig+8, ...
        const int q = qt + qi;
        const float hob = ho[tt];
        for (int i = ig; i < ng; i += 8) {
            float pcls = sem_sh[buf][qi][lab_sh[i]];
            float ce   = cent_sh[buf][qi][i];
            float gi   = giou_sh[buf][qi][i];
            float c = __fsub_rn(__fadd_rn(__fsub_rn(-pcls, hob), ce),
                                __fmul_rn(2.0f, gi));
            cost[((size_t)b * GMAX + i) * BQ + q] = c;

            // half-wave (width 32) lexicographic (val, j) min over the tile
            float bv = c; int bj = q;
#pragma unroll
            for (int off = 16; off >= 1; off >>= 1) {
                float ov = __shfl_down(bv, off, 32);
                int   oj = __shfl_down(bj, off, 32);
                if (ov < bv || (ov == bv && oj < bj)) { bv = ov; bj = oj; }
            }
            if (qi == 0)
                rowpart[((size_t)b * GMAX + i) * NTILE + (tg * TPB + tt)] =
                    make_float2(bv, __int_as_float(bj));
        }
    }
}

// ---------------- Kernel 2: JV Hungarian solver with greedy warm start ----
// One block per batch. Dual-feasible warm start: u[i] = min_j cost[i][j],
// v = 0; greedy-assign each row to its (first-index) argmin column if free.
// Colliding rows run the exact f64 Dijkstra augmentation (first-index
// tie-break). Complementary slackness holds throughout => optimal matching;
// continuous random costs => unique optimum => matches the reference.
__launch_bounds__(BS, 1)
__global__ void matcher_kernel(const float*  __restrict__ cost,     // [B][G][Q]
                               const float2* __restrict__ rowpart,  // [B][G][NTILE]
                               const int*    __restrict__ nact,     // [B]
                               float* __restrict__ out)             // [2*B*Q]
{
    const int b    = blockIdx.x;
    const int tid  = threadIdx.x;
    const int m    = BQ;
    const int wave = tid >> 6;
    const int lane = tid & 63;

    __shared__ __align__(16) short p_lds[BQ + 8];       // matched row per col
    __shared__ __align__(16) unsigned short way_lds[BQ];
    __shared__ double u_lds[GMAX];
    __shared__ double   redv[2][NWAVE];
    __shared__ unsigned redpk[2][NWAVE];
    __shared__ int    step_i0[GMAX + 2];
    __shared__ double step_D[GMAX + 2];
    __shared__ float  rmin_v[GMAX];
    __shared__ int    rmin_j[GMAX];
    __shared__ int    unmatched[GMAX];
    __shared__ int    s_nunm;

    for (int k = tid; k < BQ + 8; k += BS) p_lds[k] = -1;
    const int ng = nact[b];
    const float* cb = cost + (size_t)b * GMAX * BQ;
    __syncthreads();

    // ---- Pass 1: per-row (min, first-argmin) from build partials ----
    for (int r = wave; r < ng; r += NWAVE) {
        const float4* rp4 =
            (const float4*)(rowpart + ((size_t)b * GMAX + r) * NTILE);
        float4 pp = rp4[lane];          // tiles 2*lane, 2*lane+1 (j-ascending)
        float bv = pp.x; int bj = __float_as_int(pp.y);
        float v2 = pp.z; int j2 = __float_as_int(pp.w);
        if (v2 < bv || (v2 == bv && j2 < bj)) { bv = v2; bj = j2; }
#pragma unroll
        for (int off = 32; off >= 1; off >>= 1) {
            float ov = __shfl_down(bv, off, 64);
            int   oj = __shfl_down(bj, off, 64);
            if (ov < bv || (ov == bv && oj < bj)) { bv = ov; bj = oj; }
        }
        if (lane == 0) { rmin_v[r] = bv; rmin_j[r] = bj; }
    }
    __syncthreads();

    // ---- duals + greedy assignment (thread 0, <=32 iters) ----
    if (tid < ng) u_lds[tid] = (double)rmin_v[tid];
    if (tid == 0) {
        int nu = 0;
        for (int i = 0; i < ng; i++) {
            int j = rmin_j[i];
            if (p_lds[j] < 0) p_lds[j] = (short)i;
            else unmatched[nu++] = i;           // ascending row order
        }
        s_nunm = nu;
    }
    __syncthreads();
    const int nunm = s_nunm;

    const double INF = (double)INFINITY;
    const int jbase = tid * CPT;
    const float4* cb4 = (const float4*)cb;

    double v_reg[CPT], minv[CPT], enterD[CPT];
    int way_reg[CPT], p_reg[CPT];
#pragma unroll
    for (int k = 0; k < CPT; k++) { v_reg[k] = 0.0; way_reg[k] = m; enterD[k] = 0.0; }

    for (int t = 0; t < nunm; t++) {
        const int ri = unmatched[t];

        // refresh p_reg (one ds_read_b128; p constant during the phase)
        int4 pv = ((const int4*)p_lds)[tid];
        p_reg[0] = (int)(short)(pv.x & 0xFFFF); p_reg[1] = pv.x >> 16;
        p_reg[2] = (int)(short)(pv.y & 0xFFFF); p_reg[3] = pv.y >> 16;
        p_reg[4] = (int)(short)(pv.z & 0xFFFF); p_reg[5] = pv.z >> 16;
        p_reg[6] = (int)(short)(pv.w & 0xFFFF); p_reg[7] = pv.w >> 16;

        // initial row load (row ri) + its u
        const float4* r4 = cb4 + (size_t)ri * (BQ / 4) + tid * 2;
        float4 c0 = r4[0];
        float4 c1 = r4[1];
        double ui0 = u_lds[ri];

#pragma unroll
        for (int k = 0; k < CPT; k++) minv[k] = INF;
        unsigned used_mask = 0;
        int i0 = ri, j0 = m, ns = 0, buf = 0, jfin;
        double D = 0.0;

        while (true) {
            float cf[CPT] = {c0.x, c0.y, c0.z, c0.w, c1.x, c1.y, c1.z, c1.w};

            // relax + per-thread lexicographic argmin (ascending k == asc. j)
            double bestv = INF;
            unsigned bestpk = ((unsigned)m << 8);
#pragma unroll
            for (int k = 0; k < CPT; k++) {
                bool un = !((used_mask >> k) & 1u);
                double cur = ((double)cf[k] - ui0) - v_reg[k];
                bool better = un && (cur < minv[k]);
                if (better) { minv[k] = cur; way_reg[k] = j0; }
                double mv = un ? minv[k] : INF;
                if (mv < bestv) {
                    bestv = mv;
                    bestpk = (((unsigned)(jbase + k)) << 8) | (unsigned)(p_reg[k] + 1);
                }
            }

            // wave-level lexicographic (val, packed-j) min
#pragma unroll
            for (int off = 32; off >= 1; off >>= 1) {
                double   ov  = __shfl_down(bestv, off, 64);
                unsigned opk = __shfl_down(bestpk, off, 64);
                if (ov < bestv || (ov == bestv && opk < bestpk)) { bestv = ov; bestpk = opk; }
            }
            if (lane == 0) { redv[buf][wave] = bestv; redpk[buf][wave] = bestpk; }
            __syncthreads();                               // the ONLY barrier

            // redundant final reduce on every thread (LDS broadcast reads)
            double delta = redv[buf][0]; unsigned pk = redpk[buf][0];
#pragma unroll
            for (int w = 1; w < NWAVE; w++) {
                double ov = redv[buf][w]; unsigned opk = redpk[buf][w];
                if (ov < delta || (ov == delta && opk < pk)) { delta = ov; pk = opk; }
            }
            const int j1 = (int)(pk >> 8);
            const int pi = (int)(pk & 0xFFu) - 1;

            if (tid == 0) { step_i0[ns] = i0; step_D[ns] = D; }
            D += delta;
            ns++;

            if (pi < 0) { jfin = j1; break; }

            // prefetch next row + its u under the update shadow
            const float4* n4 = cb4 + (size_t)pi * (BQ / 4) + tid * 2;
            c0 = n4[0];
            c1 = n4[1];
            ui0 = u_lds[pi];

#pragma unroll
            for (int k = 0; k < CPT; k++)
                if (!((used_mask >> k) & 1u)) minv[k] -= delta;

            unsigned kk = (unsigned)(j1 - jbase);
            if (kk < CPT) { used_mask |= (1u << kk); enterD[kk] = D; }

            i0 = pi; j0 = j1; buf ^= 1;
        }

        // closed-form dual updates (same f64 values as per-step updates)
#pragma unroll
        for (int k = 0; k < CPT; k++)
            if ((used_mask >> k) & 1u) v_reg[k] -= (D - enterD[k]);

        // dump way_reg as one packed 16B LDS write
        int4 wv;
        wv.x = (way_reg[0] & 0xFFFF) | (way_reg[1] << 16);
        wv.y = (way_reg[2] & 0xFFFF) | (way_reg[3] << 16);
        wv.z = (way_reg[4] & 0xFFFF) | (way_reg[5] << 16);
        wv.w = (way_reg[6] & 0xFFFF) | (way_reg[7] << 16);
        ((int4*)way_lds)[tid] = wv;

        __syncthreads();   // way/step logs visible to all
        if (tid < ns) u_lds[step_i0[tid]] += D - step_D[tid];  // distinct rows
        if (tid == 0) {
            int jc = jfin;
            while (jc != m) {
                int jp = (int)way_lds[jc];
                p_lds[jc] = (jp == m) ? (short)ri : p_lds[jp];
                jc = jp;
            }
        }
        __syncthreads();
    }

    // ---- write outputs: [per_prop (B*Q), mask (B*Q)] as float ----
#pragma unroll
    for (int k = 0; k < CPT; k++) {
        int j = jbase + k;
        short pj = p_lds[j];
        out[(size_t)b * BQ + j] = (pj >= 0) ? (float)pj : 0.0f;
        out[(size_t)NB * BQ + (size_t)b * BQ + j] = (pj >= 0) ? 1.0f : 0.0f;
    }
}

extern "C" void kernel_launch(void* const* d_in, const int* in_sizes, int n_in,
                              void* d_out, int out_size, void* d_ws, size_t ws_size,
                              hipStream_t stream) {
    const float* sem    = (const float*)d_in[0];  // [B,Q,C]
    const float* objp   = (const float*)d_in[1];  // [B,Q]
    const float* cent   = (const float*)d_in[2];  // [B,Q,G]
    const float* giou   = (const float*)d_in[3];  // [B,Q,G]
    const int*   labels = (const int*)d_in[4];    // [B,G]
    const int*   nact   = (const int*)d_in[5];    // [B]
    float* out  = (float*)d_out;                  // [2*B*Q]
    float*  cost    = (float*)d_ws;                               // 16 MB
    float2* rowpart = (float2*)((char*)d_ws + (size_t)16 * 1024 * 1024); // 1 MB

    dim3 bgrid(NTILE / TPB, NB);   // (16, 32) = 512 blocks, 2/CU
    build_cost_kernel<<<bgrid, BBS, 0, stream>>>(sem, objp, cent, giou,
                                                 labels, nact, cost, rowpart);
    matcher_kernel<<<NB, BS, 0, stream>>>(cost, rowpart, nact, out);
}